// Round 10
// baseline (357.305 us; speedup 1.0000x reference)
//
#include <hip/hip_runtime.h>
#include <math.h>

// Round 10 (= Round 9 re-run; infra failed, design unvalidated not refuted).
// R6's bin + R2's assembly shape (the only measured-5.7TB/s assembler).
// Ledger: every 1-block/CU 128KiB-LDS assembler ran 2.6-3 TB/s (R5-R8); R2's
// 8192x256x32KiB rows_kernel ran 5.7 TB/s (294MB/51us, measured). Revert to
// that shape. Feed it from 4-row bucket regions with an XCD-contiguous row
// mapping (row = (blk&7)*1024 + blk>>3) so the 4 rows sharing a parent slice
// are read on the SAME XCD -> slice re-reads hit that XCD's L2.
//  P1: 256 blocks x 1024 x 2 serial chunks (512 chunks, cs=ceil(m/512),
//      lambda=3.05/bucket/chunk at cap 8). Stage 2048 4-row buckets x 8-slot
//      64B lines, sentinel-padded; flush full lines; LDS ovf -> per-ROW
//      L2-resident lists (8192 cursors, 2048 lines, cold).
//  ROWS: 8192 blocks x 256 thr x 32KiB: zero row -> stream parent slice
//      (32KB uint4, filter key>>13==row) -> drain row ovf -> diag -> write row.
// entry = uint2{ key=(row<<13)|col, f32 bits }, SENT=0xFFFFFFFF. out idx == key.

#define NCHUNK   512
#define NBKT     2048          // 4-row buckets
#define BCAP     8             // slot = one 64B line
#define NROW     8192
#define OVB      512           // per-P1-chunk LDS overflow buffer
#define OVCAP    64            // per-row overflow list capacity
#define SENTK    0xFFFFFFFFu
#define GCAP     65536

// ---------------------------------------------------------------- fused path

__global__ __launch_bounds__(1024) void p1_kernel(
    const int*   __restrict__ idx,     // [2, M] int32
    const float* __restrict__ vals,    // [M]
    float scale, int m, int cs,
    uint2* __restrict__ region1,       // [NBKT][NCHUNK][BCAP]
    uint2* __restrict__ ovfreg,        // [NROW][OVCAP]
    int*   __restrict__ ovfcur,        // [NROW]
    uint2* __restrict__ glist,         // [GCAP] never-path
    int*   __restrict__ ghdr)
{
    __shared__ uint2 stage[NBKT][BCAP];    // 128 KiB
    __shared__ int   cnt[NBKT];            // 8 KiB
    __shared__ uint2 ovfst[OVB];           // 4 KiB
    __shared__ int   ovfn;
    uint2* sflat = &stage[0][0];
    const int tid = threadIdx.x;

    for (int c = 0; c < 2; ++c) {
        const int chunk = blockIdx.x * 2 + c;

        for (int f = tid; f < NBKT * BCAP; f += 1024) sflat[f] = make_uint2(SENTK, 0u);
        for (int b = tid; b < NBKT; b += 1024) cnt[b] = 0;
        if (tid == 0) ovfn = 0;
        __syncthreads();

        const int base = chunk * cs;
        int end = base + cs; if (end > m) end = m;
        for (int k = base + tid; k < end; k += 1024) {
            int i = idx[k];
            int j = idx[m + k];
            unsigned vb = __float_as_uint(vals[k] * scale);

            unsigned k1 = ((unsigned)i << 13) | (unsigned)j;
            int b1 = i >> 2;
            int p = atomicAdd(&cnt[b1], 1);
            if (p < BCAP) stage[b1][p] = make_uint2(k1, vb);
            else { int q = atomicAdd(&ovfn, 1);
                   if (q < OVB) ovfst[q] = make_uint2(k1, vb);
                   else { int g = atomicAdd(ghdr, 1); if (g < GCAP) glist[g] = make_uint2(k1, vb); } }

            unsigned k2 = ((unsigned)j << 13) | (unsigned)i;
            int b2 = j >> 2;
            p = atomicAdd(&cnt[b2], 1);
            if (p < BCAP) stage[b2][p] = make_uint2(k2, vb);
            else { int q = atomicAdd(&ovfn, 1);
                   if (q < OVB) ovfst[q] = make_uint2(k2, vb);
                   else { int g = atomicAdd(ghdr, 1); if (g < GCAP) glist[g] = make_uint2(k2, vb); } }
        }
        __syncthreads();

        // flush: 8 consecutive threads write one full 64B line per bucket slot
        for (int f = tid; f < NBKT * BCAP; f += 1024) {
            int bkt = f >> 3, e = f & 7;
            region1[((long long)bkt * NCHUNK + chunk) * BCAP + e] = sflat[f];
        }
        // LDS overflow -> per-row lists (8192 cursors over 2048 lines, cold)
        int n = ovfn; if (n > OVB) n = OVB;
        for (int e = tid; e < n; e += 1024) {
            uint2 en = ovfst[e];
            int row = en.x >> 13;
            int pos = atomicAdd(&ovfcur[row], 1);
            if (pos < OVCAP) ovfreg[row * OVCAP + pos] = en;
            else { int g = atomicAdd(ghdr, 1); if (g < GCAP) glist[g] = en; }
        }
        __syncthreads();                 // stage/ovfst reused next chunk
    }
}

__global__ __launch_bounds__(256) void rows9_kernel(
    float* __restrict__ out,
    const float* __restrict__ h_local,
    const uint2* __restrict__ region1,
    const uint2* __restrict__ ovfreg,
    const int*   __restrict__ ovfcur,
    const uint2* __restrict__ glist,
    const int*   __restrict__ ghdr)
{
    __shared__ float srow[8192];                   // 32 KiB -> ~5 blocks/CU
    float4* s4 = reinterpret_cast<float4*>(srow);
    const int b   = blockIdx.x;
    // XCD-contiguous mapping: XCD x (b%8 under round-robin dispatch) owns rows
    // [x*1024, (x+1)*1024) in order -> 4 rows of one bucket read on one XCD.
    const int row = ((b & 7) << 10) | (b >> 3);

    const float4 z = make_float4(0.f, 0.f, 0.f, 0.f);
    for (int c = threadIdx.x; c < 2048; c += 256) s4[c] = z;
    __syncthreads();

    // stream the parent 4-row bucket slice (32 KB), filter to our row
    const uint4* src = reinterpret_cast<const uint4*>(
        region1 + (long long)(row >> 2) * NCHUNK * BCAP);
    const unsigned ru = (unsigned)row;
    for (int e = threadIdx.x; e < (NCHUNK * BCAP) / 2; e += 256) {
        uint4 en = src[e];
        if ((en.x >> 13) == ru) srow[en.x & 8191] = __uint_as_float(en.y);
        if ((en.z >> 13) == ru) srow[en.z & 8191] = __uint_as_float(en.w);
    }
    // drain own overflow list (~1 entry expected)
    int n = ovfcur[row]; if (n > OVCAP) n = OVCAP;
    for (int e = threadIdx.x; e < n; e += 256) {
        uint2 en = ovfreg[row * OVCAP + e];
        srow[en.x & 8191] = __uint_as_float(en.y);
    }
    // never-path spill
    int gn = ghdr[0];
    if (gn > 0) {
        if (gn > GCAP) gn = GCAP;
        for (int e = threadIdx.x; e < gn; e += 256) {
            uint2 en = glist[e];
            if ((en.x >> 13) == ru) srow[en.x & 8191] = __uint_as_float(en.y);
        }
    }
    if (threadIdx.x == 0) srow[row] = h_local[row];   // diagonal
    __syncthreads();

    float4* orow = reinterpret_cast<float4*>(out + ((long long)row << 13));
    for (int c = threadIdx.x; c < 2048; c += 256) orow[c] = s4[c];
}

// ---------------------------------------------------------------- fallbacks

__global__ __launch_bounds__(256) void init_counts_kernel(
    float* __restrict__ out, int d, int logd)
{
    int r = blockIdx.x * blockDim.x + threadIdx.x;
    if (r < d) reinterpret_cast<int*>(out)[(long long)r << logd] = 0;
}

__global__ __launch_bounds__(256) void bin_kernel(
    float* __restrict__ out,
    const int*   __restrict__ idx,
    const float* __restrict__ vals,
    float scale, int m, int logd, int cap)
{
    int k = blockIdx.x * blockDim.x + threadIdx.x;
    if (k >= m) return;
    int i = idx[k];
    int j = idx[m + k];
    unsigned vb = __float_as_uint(vals[k] * scale);
    int* cnt_i = reinterpret_cast<int*>(out) + ((long long)i << logd);
    int* cnt_j = reinterpret_cast<int*>(out) + ((long long)j << logd);
    int p1 = atomicAdd(cnt_i, 1);
    if (p1 < cap)
        *reinterpret_cast<uint2*>(out + ((long long)i << logd) + 2 + 2 * p1) =
            make_uint2((unsigned)j, vb);
    int p2 = atomicAdd(cnt_j, 1);
    if (p2 < cap)
        *reinterpret_cast<uint2*>(out + ((long long)j << logd) + 2 + 2 * p2) =
            make_uint2((unsigned)i, vb);
}

__global__ __launch_bounds__(256) void rows_kernel(
    float* __restrict__ out,
    const float* __restrict__ h_local,
    int logd, int cap)
{
    __shared__ float srow[8192];
    const int d  = 1 << logd;
    const int n4 = d >> 2;
    float4* s4 = reinterpret_cast<float4*>(srow);
    const int r = blockIdx.x;
    float* grow = out + ((long long)r << logd);
    const float4 z = make_float4(0.f, 0.f, 0.f, 0.f);
    for (int c = threadIdx.x; c < n4; c += blockDim.x) s4[c] = z;
    __syncthreads();
    int cnt = reinterpret_cast<const int*>(grow)[0];
    if (cnt > cap) cnt = cap;
    const uint2* eb = reinterpret_cast<const uint2*>(grow + 2);
    for (int e = threadIdx.x; e < cnt; e += blockDim.x) {
        uint2 p = eb[e];
        srow[p.x] = __uint_as_float(p.y);
    }
    if (threadIdx.x == 0) srow[r] = h_local[r];
    __syncthreads();
    for (int c = threadIdx.x; c < n4; c += blockDim.x)
        reinterpret_cast<float4*>(grow)[c] = s4[c];
}

__global__ __launch_bounds__(256) void fill_diag_kernel(
    float* __restrict__ out, const float* __restrict__ h_local,
    int d, long long n)
{
    long long t = (long long)blockIdx.x * blockDim.x + threadIdx.x;
    if (t >= n) return;
    long long row = t / d;
    long long col = t - row * d;
    out[t] = (row == col) ? h_local[row] : 0.f;
}

__global__ __launch_bounds__(256) void scatter_kernel(
    float* __restrict__ out,
    const int* __restrict__ idx,
    const float* __restrict__ vals,
    float scale, int m, int d)
{
    int k = blockIdx.x * blockDim.x + threadIdx.x;
    if (k >= m) return;
    int i = idx[k];
    int j = idx[m + k];
    float v = vals[k] * scale;
    out[(long long)i * d + j] = v;
    out[(long long)j * d + i] = v;
}

// ---------------------------------------------------------------- launch

extern "C" void kernel_launch(void* const* d_in, const int* in_sizes, int n_in,
                              void* d_out, int out_size, void* d_ws, size_t ws_size,
                              hipStream_t stream) {
    const float* h_local = (const float*)d_in[0];
    const float* V_int   = (const float*)d_in[1];
    const int*   idx     = (const int*)d_in[2];

    const int d = in_sizes[0];            // 8192
    const int m = in_sizes[1];            // 1,600,000

    int logd = 0;
    while ((1 << logd) < d) ++logd;
    const bool pow2 = ((1 << logd) == d);

    const float iscale = (float)(1.0 - 0.2 / sqrt(log((double)d)));
    float* out = (float*)d_out;
    const int block = 256;

    // ws layout: [ghdr @0][ovfcur @4096: NROW*4=32KB] -> memset first 36.5KB
    //            [glist 512KB @40960][ovfreg 4MB][region1 64MB]
    const size_t off_ovfcur = 4096;
    const size_t hdr_bytes  = off_ovfcur + (size_t)NROW * 4;         // 36864
    const size_t off_glist  = 40960;
    const size_t off_ovfreg = off_glist + (size_t)GCAP * sizeof(uint2);
    const size_t off_r1     = off_ovfreg + (size_t)NROW * OVCAP * sizeof(uint2);
    const size_t ws_need    = off_r1 + (size_t)NBKT * NCHUNK * BCAP * sizeof(uint2);

    const bool path10 = (d == 8192) && (m > 0) && (m <= 2200000) &&
                        (d_ws != nullptr) && (ws_size >= ws_need);

    if (path10) {
        char* ws = (char*)d_ws;
        int*   ghdr    = (int*)ws;
        int*   ovfcur  = (int*)(ws + off_ovfcur);
        uint2* glist   = (uint2*)(ws + off_glist);
        uint2* ovfreg  = (uint2*)(ws + off_ovfreg);
        uint2* region1 = (uint2*)(ws + off_r1);

        const int cs = (m + NCHUNK - 1) / NCHUNK;        // pairs per chunk

        hipMemsetAsync(ws, 0, hdr_bytes, stream);
        p1_kernel<<<NCHUNK / 2, 1024, 0, stream>>>(idx, V_int, iscale, m, cs,
                                                   region1, ovfreg, ovfcur,
                                                   glist, ghdr);
        rows9_kernel<<<NROW, 256, 0, stream>>>(out, h_local, region1,
                                               ovfreg, ovfcur, glist, ghdr);
    } else if (pow2 && d >= 1024 && d <= 8192 &&
               ((long long)m * 2 / d) < (long long)((d - 2) / 2) / 2) {
        const int cap = (d - 2) / 2;
        init_counts_kernel<<<(d + block - 1) / block, block, 0, stream>>>(out, d, logd);
        bin_kernel<<<(m + block - 1) / block, block, 0, stream>>>(out, idx, V_int,
                                                                  iscale, m, logd, cap);
        rows_kernel<<<d, block, 0, stream>>>(out, h_local, logd, cap);
    } else {
        const long long n = (long long)d * d;
        const long long grid_fill = (n + block - 1) / block;
        fill_diag_kernel<<<(dim3)(unsigned)grid_fill, block, 0, stream>>>(out, h_local, d, n);
        const int grid_sc = (m + block - 1) / block;
        scatter_kernel<<<grid_sc, block, 0, stream>>>(out, idx, V_int, iscale, m, d);
    }
}

// Round 11
// 337.556 us; speedup vs baseline: 1.0585x; 1.0585x over previous
//
#include <hip/hip_runtime.h>
#include <math.h>

// Round 11: R6 (measured best, 320us) + three targeted micro-fixes.
// Ledger conclusion: assembly time is TRAFFIC-dominated, not shape-dominated
// (R7 +51MB=+8us, R10 +200MB=+37us, R8 serialized=+29us). R6's zero-redundancy
// bucket==block structure is optimal; keep it byte-identical except:
//  (1) p1: 196 blocks x 2 serial chunks (392 chunks, ONE scheduling round;
//      R6's 391 blocks ran 1.53 rounds, 2nd round 53% utilized). Overflow
//      stays ATOMIC-FREE per-chunk (R8/R10 regressions came from cursor
//      atomics + p2 changes, not the serial-chunk form).
//  (2) zero_hdr kernel -> hipMemsetAsync (capture-legal, proven R7/8/10).
//  (3) p2: 512 threads (8-wave barriers instead of 16; streaming saturates
//      at ~3 waves/CU per fillBuffer evidence).
//  P1: stage 2048 4-row buckets x 8-slot 64B lines, sentinel-padded; flush
//      full lines to region1[bucket][chunk][8]; LDS ovf -> ovf[chunk][512].
//  P2: 2048 blocks, bucket==block: zero 128KiB LDS -> stream own 25KB slice
//      (no filter needed: every non-sentinel entry belongs) -> diag -> write.
//  P3: ovf_scatter drains per-chunk lists (~56 entries each) AFTER p2.
// entry = uint2{ key=(row<<13)|col, f32 bits }, SENT=0xFFFFFFFF. out idx == key.

#define NCHUNKS  392
#define NBKT     2048          // 4-row buckets
#define BCAP     8             // slot = one 64B line
#define OVB      512           // per-chunk overflow region capacity
#define SENTK    0xFFFFFFFFu
#define GCAP     65536

// ---------------------------------------------------------------- fused path

__global__ __launch_bounds__(1024) void p1_kernel(
    const int*   __restrict__ idx,     // [2, M] int32
    const float* __restrict__ vals,    // [M]
    float scale, int m, int cs,
    uint2* __restrict__ region1,       // [NBKT][NCHUNKS][BCAP]
    uint2* __restrict__ ovf,           // [NCHUNKS][OVB]
    int*   __restrict__ ovfc,          // [NCHUNKS]
    uint2* __restrict__ glist,         // [GCAP] never-path
    int*   __restrict__ ghdr)
{
    __shared__ uint2 stage[NBKT][BCAP];    // 128 KiB
    __shared__ int   cnt[NBKT];            // 8 KiB
    __shared__ uint2 ovfst[OVB];           // 4 KiB
    __shared__ int   ovfn;
    uint2* sflat = &stage[0][0];
    const int tid = threadIdx.x;

    for (int c = 0; c < 2; ++c) {
        const int chunk = blockIdx.x * 2 + c;

        for (int f = tid; f < NBKT * BCAP; f += 1024) sflat[f] = make_uint2(SENTK, 0u);
        for (int b = tid; b < NBKT; b += 1024) cnt[b] = 0;
        if (tid == 0) ovfn = 0;
        __syncthreads();

        const int base = chunk * cs;
        int end = base + cs; if (end > m) end = m;
        for (int k = base + tid; k < end; k += 1024) {
            int i = idx[k];
            int j = idx[m + k];
            unsigned vb = __float_as_uint(vals[k] * scale);

            unsigned k1 = ((unsigned)i << 13) | (unsigned)j;
            int b1 = i >> 2;
            int p = atomicAdd(&cnt[b1], 1);
            if (p < BCAP) stage[b1][p] = make_uint2(k1, vb);
            else { int q = atomicAdd(&ovfn, 1);
                   if (q < OVB) ovfst[q] = make_uint2(k1, vb);
                   else { int g = atomicAdd(ghdr, 1); if (g < GCAP) glist[g] = make_uint2(k1, vb); } }

            unsigned k2 = ((unsigned)j << 13) | (unsigned)i;
            int b2 = j >> 2;
            p = atomicAdd(&cnt[b2], 1);
            if (p < BCAP) stage[b2][p] = make_uint2(k2, vb);
            else { int q = atomicAdd(&ovfn, 1);
                   if (q < OVB) ovfst[q] = make_uint2(k2, vb);
                   else { int g = atomicAdd(ghdr, 1); if (g < GCAP) glist[g] = make_uint2(k2, vb); } }
        }
        __syncthreads();

        // flush: 8 consecutive threads write one full 64B line per bucket slot
        for (int f = tid; f < NBKT * BCAP; f += 1024) {
            int bkt = f >> 3, e = f & 7;
            region1[((long long)bkt * NCHUNKS + chunk) * BCAP + e] = sflat[f];
        }
        // flush per-chunk LDS overflow (atomic-free, per-chunk region)
        int n = ovfn; if (n > OVB) n = OVB;
        for (int e = tid; e < n; e += 1024)
            ovf[(long long)chunk * OVB + e] = ovfst[e];
        if (tid == 0) ovfc[chunk] = n;
        __syncthreads();                 // stage/ovfst reused next chunk
    }
}

__global__ __launch_bounds__(512) void p2_kernel(
    float* __restrict__ out,
    const float* __restrict__ h_local,
    const uint2* __restrict__ region1)
{
    __shared__ float srow[4 * 8192];               // 128 KiB: one 4-row band
    float4* s4 = reinterpret_cast<float4*>(srow);
    const int band = blockIdx.x;                   // == bucket

    for (int c = threadIdx.x; c < 8192; c += 512)
        s4[c] = make_float4(0.f, 0.f, 0.f, 0.f);
    __syncthreads();

    // contiguous 25KB gather of this band's slice (2 entries / uint4);
    // no filter needed: every non-sentinel entry belongs to this band.
    const uint4* src = reinterpret_cast<const uint4*>(
        region1 + (long long)band * NCHUNKS * BCAP);
    const int n2 = (NCHUNKS * BCAP) >> 1;
    for (int e = threadIdx.x; e < n2; e += 512) {
        uint4 en = src[e];
        if (en.x != SENTK) srow[en.x & 0x7FFF] = __uint_as_float(en.y);
        if (en.z != SENTK) srow[en.z & 0x7FFF] = __uint_as_float(en.w);
    }
    if (threadIdx.x < 4) {
        int r = (band << 2) + threadIdx.x;
        srow[((unsigned)threadIdx.x << 13) | (unsigned)r] = h_local[r];
    }
    __syncthreads();

    float4* orow = reinterpret_cast<float4*>(out + ((long long)band << 15));
    for (int c = threadIdx.x; c < 8192; c += 512)
        orow[c] = s4[c];
}

__global__ __launch_bounds__(256) void ovf_scatter_kernel(
    float* __restrict__ out,
    const uint2* __restrict__ ovf,     // [NCHUNKS][OVB]
    const int*   __restrict__ ovfc,    // [NCHUNKS]
    const uint2* __restrict__ glist,
    const int*   __restrict__ ghdr)
{
    const int blk = blockIdx.x;
    int n = ovfc[blk]; if (n > OVB) n = OVB;
    for (int e = threadIdx.x; e < n; e += 256) {
        uint2 en = ovf[(long long)blk * OVB + e];
        out[en.x] = __uint_as_float(en.y);         // d=2^13: flat index == key
    }
    if (blk == 0) {                                // never-path spill
        int g = ghdr[0]; if (g > GCAP) g = GCAP;
        for (int e = threadIdx.x; e < g; e += 256) {
            uint2 en = glist[e];
            out[en.x] = __uint_as_float(en.y);
        }
    }
}

// ---------------------------------------------------------------- fallbacks

__global__ __launch_bounds__(256) void init_counts_kernel(
    float* __restrict__ out, int d, int logd)
{
    int r = blockIdx.x * blockDim.x + threadIdx.x;
    if (r < d) reinterpret_cast<int*>(out)[(long long)r << logd] = 0;
}

__global__ __launch_bounds__(256) void bin_kernel(
    float* __restrict__ out,
    const int*   __restrict__ idx,
    const float* __restrict__ vals,
    float scale, int m, int logd, int cap)
{
    int k = blockIdx.x * blockDim.x + threadIdx.x;
    if (k >= m) return;
    int i = idx[k];
    int j = idx[m + k];
    unsigned vb = __float_as_uint(vals[k] * scale);
    int* cnt_i = reinterpret_cast<int*>(out) + ((long long)i << logd);
    int* cnt_j = reinterpret_cast<int*>(out) + ((long long)j << logd);
    int p1 = atomicAdd(cnt_i, 1);
    if (p1 < cap)
        *reinterpret_cast<uint2*>(out + ((long long)i << logd) + 2 + 2 * p1) =
            make_uint2((unsigned)j, vb);
    int p2 = atomicAdd(cnt_j, 1);
    if (p2 < cap)
        *reinterpret_cast<uint2*>(out + ((long long)j << logd) + 2 + 2 * p2) =
            make_uint2((unsigned)i, vb);
}

__global__ __launch_bounds__(256) void rows_kernel(
    float* __restrict__ out,
    const float* __restrict__ h_local,
    int logd, int cap)
{
    __shared__ float srow[8192];
    const int d  = 1 << logd;
    const int n4 = d >> 2;
    float4* s4 = reinterpret_cast<float4*>(srow);
    const int r = blockIdx.x;
    float* grow = out + ((long long)r << logd);
    const float4 z = make_float4(0.f, 0.f, 0.f, 0.f);
    for (int c = threadIdx.x; c < n4; c += blockDim.x) s4[c] = z;
    __syncthreads();
    int cnt = reinterpret_cast<const int*>(grow)[0];
    if (cnt > cap) cnt = cap;
    const uint2* eb = reinterpret_cast<const uint2*>(grow + 2);
    for (int e = threadIdx.x; e < cnt; e += blockDim.x) {
        uint2 p = eb[e];
        srow[p.x] = __uint_as_float(p.y);
    }
    if (threadIdx.x == 0) srow[r] = h_local[r];
    __syncthreads();
    for (int c = threadIdx.x; c < n4; c += blockDim.x)
        reinterpret_cast<float4*>(grow)[c] = s4[c];
}

__global__ __launch_bounds__(256) void fill_diag_kernel(
    float* __restrict__ out, const float* __restrict__ h_local,
    int d, long long n)
{
    long long t = (long long)blockIdx.x * blockDim.x + threadIdx.x;
    if (t >= n) return;
    long long row = t / d;
    long long col = t - row * d;
    out[t] = (row == col) ? h_local[row] : 0.f;
}

__global__ __launch_bounds__(256) void scatter_kernel(
    float* __restrict__ out,
    const int* __restrict__ idx,
    const float* __restrict__ vals,
    float scale, int m, int d)
{
    int k = blockIdx.x * blockDim.x + threadIdx.x;
    if (k >= m) return;
    int i = idx[k];
    int j = idx[m + k];
    float v = vals[k] * scale;
    out[(long long)i * d + j] = v;
    out[(long long)j * d + i] = v;
}

// ---------------------------------------------------------------- launch

extern "C" void kernel_launch(void* const* d_in, const int* in_sizes, int n_in,
                              void* d_out, int out_size, void* d_ws, size_t ws_size,
                              hipStream_t stream) {
    const float* h_local = (const float*)d_in[0];
    const float* V_int   = (const float*)d_in[1];
    const int*   idx     = (const int*)d_in[2];

    const int d = in_sizes[0];            // 8192
    const int m = in_sizes[1];            // 1,600,000

    int logd = 0;
    while ((1 << logd) < d) ++logd;
    const bool pow2 = ((1 << logd) == d);

    const float iscale = (float)(1.0 - 0.2 / sqrt(log((double)d)));
    float* out = (float*)d_out;
    const int block = 256;

    // ws layout: [ghdr @0][ovfc @4096: 392*4=1568B] -> memset first 5664B
    //            [glist 512KB @8192][ovf @532480: 392*512*8=1.6MB][region1 @2138112: 51.4MB]
    const size_t off_ovfc  = 4096;
    const size_t hdr_bytes = off_ovfc + (size_t)NCHUNKS * 4;
    const size_t off_glist = 8192;
    const size_t off_ovf   = off_glist + (size_t)GCAP * sizeof(uint2);
    const size_t off_r1    = off_ovf + (size_t)NCHUNKS * OVB * sizeof(uint2);
    const size_t ws_need   = off_r1 + (size_t)NBKT * NCHUNKS * BCAP * sizeof(uint2);

    const bool path11 = (d == 8192) && (m > 0) && (m <= 2000000) &&
                        (d_ws != nullptr) && (ws_size >= ws_need);

    if (path11) {
        char* ws = (char*)d_ws;
        int*   ghdr    = (int*)ws;
        int*   ovfc    = (int*)(ws + off_ovfc);
        uint2* glist   = (uint2*)(ws + off_glist);
        uint2* ovf     = (uint2*)(ws + off_ovf);
        uint2* region1 = (uint2*)(ws + off_r1);

        const int cs = (m + NCHUNKS - 1) / NCHUNKS;      // pairs per chunk

        hipMemsetAsync(ws, 0, hdr_bytes, stream);
        p1_kernel<<<NCHUNKS / 2, 1024, 0, stream>>>(idx, V_int, iscale, m, cs,
                                                    region1, ovf, ovfc,
                                                    glist, ghdr);
        p2_kernel<<<NBKT, 512, 0, stream>>>(out, h_local, region1);
        ovf_scatter_kernel<<<NCHUNKS, 256, 0, stream>>>(out, ovf, ovfc, glist, ghdr);
    } else if (pow2 && d >= 1024 && d <= 8192 &&
               ((long long)m * 2 / d) < (long long)((d - 2) / 2) / 2) {
        const int cap = (d - 2) / 2;
        init_counts_kernel<<<(d + block - 1) / block, block, 0, stream>>>(out, d, logd);
        bin_kernel<<<(m + block - 1) / block, block, 0, stream>>>(out, idx, V_int,
                                                                  iscale, m, logd, cap);
        rows_kernel<<<d, block, 0, stream>>>(out, h_local, logd, cap);
    } else {
        const long long n = (long long)d * d;
        const long long grid_fill = (n + block - 1) / block;
        fill_diag_kernel<<<(dim3)(unsigned)grid_fill, block, 0, stream>>>(out, h_local, d, n);
        const int grid_sc = (m + block - 1) / block;
        scatter_kernel<<<grid_sc, block, 0, stream>>>(out, idx, V_int, iscale, m, d);
    }
}

// Round 12
// 328.838 us; speedup vs baseline: 1.0866x; 1.0265x over previous
//
#include <hip/hip_runtime.h>
#include <math.h>

// Round 12: packed compacting flush + R2-shaped assembler (the untested cell).
// Ledger: R2's rows (256thr/32KiB, packed 100%-fill read) = 5.7 TB/s measured;
// R6-p2 (1024thr/128KiB, 50%-sentinel read) = 3.2 TB/s; R10 (R2 shape, UNpacked
// 4x-redundant read) = 3 TB/s. Test packed+shape together:
//  P1: R6 binning core (391 blocks x 4096 pairs, stage[2048][8], cap 8) but
//      COMPACTING flush: per bucket reserve cnt slots via atomicAdd(gcur[b])
//      (2048 cursors on 2048 distinct lines - cold), write only real entries.
//      Packed region = 26 MB, no sentinels, no sentinel-init pass. Bin-time
//      overflow appends through the same cursors -> ovf kernel deleted.
//  P2: 2048 blocks x 256 thr x 32 KiB; block=bucket processes its 4 rows
//      SEQUENTIALLY: packed 12.5 KB list read once from HBM, L1-resident for
//      rows 1-3. Per row: zero -> scan/filter (key>>13==row) -> diag -> 32 KiB
//      coalesced write.
// entry = uint2{ key=(row<<13)|col, f32 bits of val*scale }. out idx == key.

#define P1_PAIRS 4096
#define NBKT     2048          // 4-row buckets
#define BCAP     8
#define PCAP     2048          // packed entries per bucket (exp 1563, +12 sigma)
#define GCAP     65536

// ---------------------------------------------------------------- fused path

__global__ __launch_bounds__(1024) void p1_kernel(
    const int*   __restrict__ idx,     // [2, M] int32
    const float* __restrict__ vals,    // [M]
    float scale, int m,
    uint2* __restrict__ packed,        // [NBKT][PCAP]
    int*   __restrict__ gcur,          // [NBKT]
    uint2* __restrict__ glist,         // [GCAP] never-path
    int*   __restrict__ ghdr)
{
    __shared__ uint2 stage[NBKT][BCAP];    // 128 KiB
    __shared__ int   cnt[NBKT];            // 8 KiB
    __shared__ int   off[NBKT];            // 8 KiB
    const int tid = threadIdx.x;

    for (int b = tid; b < NBKT; b += 1024) cnt[b] = 0;
    __syncthreads();

    const int base = blockIdx.x * P1_PAIRS;
#pragma unroll
    for (int it = 0; it < P1_PAIRS / 1024; ++it) {
        int k = base + it * 1024 + tid;
        if (k < m) {
            int i = idx[k];
            int j = idx[m + k];
            unsigned vb = __float_as_uint(vals[k] * scale);

            unsigned k1 = ((unsigned)i << 13) | (unsigned)j;
            int b1 = i >> 2;
            int p = atomicAdd(&cnt[b1], 1);
            if (p < BCAP) stage[b1][p] = make_uint2(k1, vb);
            else { int g = atomicAdd(&gcur[b1], 1);
                   if (g < PCAP) packed[(long long)b1 * PCAP + g] = make_uint2(k1, vb);
                   else { int q = atomicAdd(ghdr, 1); if (q < GCAP) glist[q] = make_uint2(k1, vb); } }

            unsigned k2 = ((unsigned)j << 13) | (unsigned)i;
            int b2 = j >> 2;
            p = atomicAdd(&cnt[b2], 1);
            if (p < BCAP) stage[b2][p] = make_uint2(k2, vb);
            else { int g = atomicAdd(&gcur[b2], 1);
                   if (g < PCAP) packed[(long long)b2 * PCAP + g] = make_uint2(k2, vb);
                   else { int q = atomicAdd(ghdr, 1); if (q < GCAP) glist[q] = make_uint2(k2, vb); } }
        }
    }
    __syncthreads();

    // phase A: reserve packed slots (one atomic per bucket, 2048 distinct lines)
    for (int b = tid; b < NBKT; b += 1024) {
        int c = cnt[b]; if (c > BCAP) c = BCAP;
        off[b] = (c > 0) ? atomicAdd(&gcur[b], c) : 0;
    }
    __syncthreads();

    // phase B: compacted write (only real entries, no sentinels)
    for (int f = tid; f < NBKT * BCAP; f += 1024) {
        int b = f >> 3, e = f & 7;
        int c = cnt[b]; if (c > BCAP) c = BCAP;
        if (e < c) {
            int pos = off[b] + e;
            if (pos < PCAP) packed[(long long)b * PCAP + pos] = stage[b][e];
            else { int q = atomicAdd(ghdr, 1); if (q < GCAP) glist[q] = stage[b][e]; }
        }
    }
}

__global__ __launch_bounds__(256) void p2_kernel(
    float* __restrict__ out,
    const float* __restrict__ h_local,
    const uint2* __restrict__ packed,
    const int*   __restrict__ gcur,
    const uint2* __restrict__ glist,
    const int*   __restrict__ ghdr)
{
    __shared__ float srow[8192];                   // 32 KiB -> ~4-5 blocks/CU
    float4* s4 = reinterpret_cast<float4*>(srow);
    const int b   = blockIdx.x;                    // bucket: rows 4b..4b+3
    const int tid = threadIdx.x;

    int n = gcur[b]; if (n > PCAP) n = PCAP;
    int gn = ghdr[0]; if (gn > GCAP) gn = GCAP;
    const uint2* pb = packed + (long long)b * PCAP;

    const float4 z = make_float4(0.f, 0.f, 0.f, 0.f);
    for (int r4 = 0; r4 < 4; ++r4) {
        const int row = (b << 2) + r4;
        const unsigned ru = (unsigned)row;

        for (int c = tid; c < 2048; c += 256) s4[c] = z;
        __syncthreads();

        // packed list: 12.5 KB, HBM once (r4==0), L1-resident afterwards
        for (int e = tid; e < n; e += 256) {
            uint2 en = pb[e];
            if ((en.x >> 13) == ru) srow[en.x & 8191] = __uint_as_float(en.y);
        }
        if (gn > 0) {                              // never-path spill
            for (int e = tid; e < gn; e += 256) {
                uint2 en = glist[e];
                if ((en.x >> 13) == ru) srow[en.x & 8191] = __uint_as_float(en.y);
            }
        }
        if (tid == 0) srow[row] = h_local[row];    // diagonal (i>j => never hit)
        __syncthreads();

        float4* orow = reinterpret_cast<float4*>(out + ((long long)row << 13));
        for (int c = tid; c < 2048; c += 256) orow[c] = s4[c];
        __syncthreads();                           // srow reused next row
    }
}

// ---------------------------------------------------------------- fallbacks

__global__ __launch_bounds__(256) void init_counts_kernel(
    float* __restrict__ out, int d, int logd)
{
    int r = blockIdx.x * blockDim.x + threadIdx.x;
    if (r < d) reinterpret_cast<int*>(out)[(long long)r << logd] = 0;
}

__global__ __launch_bounds__(256) void bin_kernel(
    float* __restrict__ out,
    const int*   __restrict__ idx,
    const float* __restrict__ vals,
    float scale, int m, int logd, int cap)
{
    int k = blockIdx.x * blockDim.x + threadIdx.x;
    if (k >= m) return;
    int i = idx[k];
    int j = idx[m + k];
    unsigned vb = __float_as_uint(vals[k] * scale);
    int* cnt_i = reinterpret_cast<int*>(out) + ((long long)i << logd);
    int* cnt_j = reinterpret_cast<int*>(out) + ((long long)j << logd);
    int p1 = atomicAdd(cnt_i, 1);
    if (p1 < cap)
        *reinterpret_cast<uint2*>(out + ((long long)i << logd) + 2 + 2 * p1) =
            make_uint2((unsigned)j, vb);
    int p2 = atomicAdd(cnt_j, 1);
    if (p2 < cap)
        *reinterpret_cast<uint2*>(out + ((long long)j << logd) + 2 + 2 * p2) =
            make_uint2((unsigned)i, vb);
}

__global__ __launch_bounds__(256) void rows_kernel(
    float* __restrict__ out,
    const float* __restrict__ h_local,
    int logd, int cap)
{
    __shared__ float srow[8192];
    const int d  = 1 << logd;
    const int n4 = d >> 2;
    float4* s4 = reinterpret_cast<float4*>(srow);
    const int r = blockIdx.x;
    float* grow = out + ((long long)r << logd);
    const float4 z = make_float4(0.f, 0.f, 0.f, 0.f);
    for (int c = threadIdx.x; c < n4; c += blockDim.x) s4[c] = z;
    __syncthreads();
    int cnt = reinterpret_cast<const int*>(grow)[0];
    if (cnt > cap) cnt = cap;
    const uint2* eb = reinterpret_cast<const uint2*>(grow + 2);
    for (int e = threadIdx.x; e < cnt; e += blockDim.x) {
        uint2 p = eb[e];
        srow[p.x] = __uint_as_float(p.y);
    }
    if (threadIdx.x == 0) srow[r] = h_local[r];
    __syncthreads();
    for (int c = threadIdx.x; c < n4; c += blockDim.x)
        reinterpret_cast<float4*>(grow)[c] = s4[c];
}

__global__ __launch_bounds__(256) void fill_diag_kernel(
    float* __restrict__ out, const float* __restrict__ h_local,
    int d, long long n)
{
    long long t = (long long)blockIdx.x * blockDim.x + threadIdx.x;
    if (t >= n) return;
    long long row = t / d;
    long long col = t - row * d;
    out[t] = (row == col) ? h_local[row] : 0.f;
}

__global__ __launch_bounds__(256) void scatter_kernel(
    float* __restrict__ out,
    const int* __restrict__ idx,
    const float* __restrict__ vals,
    float scale, int m, int d)
{
    int k = blockIdx.x * blockDim.x + threadIdx.x;
    if (k >= m) return;
    int i = idx[k];
    int j = idx[m + k];
    float v = vals[k] * scale;
    out[(long long)i * d + j] = v;
    out[(long long)j * d + i] = v;
}

// ---------------------------------------------------------------- launch

extern "C" void kernel_launch(void* const* d_in, const int* in_sizes, int n_in,
                              void* d_out, int out_size, void* d_ws, size_t ws_size,
                              hipStream_t stream) {
    const float* h_local = (const float*)d_in[0];
    const float* V_int   = (const float*)d_in[1];
    const int*   idx     = (const int*)d_in[2];

    const int d = in_sizes[0];            // 8192
    const int m = in_sizes[1];            // 1,600,000

    int logd = 0;
    while ((1 << logd) < d) ++logd;
    const bool pow2 = ((1 << logd) == d);

    const float iscale = (float)(1.0 - 0.2 / sqrt(log((double)d)));
    float* out = (float*)d_out;
    const int block = 256;

    // ws layout: [gcur 8KB @0][ghdr @8192][pad to 12288] -> memset 12 KB
    //            [glist 512KB @12288][packed 32MB @536576]
    const size_t off_ghdr   = 8192;
    const size_t hdr_bytes  = 12288;
    const size_t off_glist  = 12288;
    const size_t off_packed = off_glist + (size_t)GCAP * sizeof(uint2);
    const size_t ws_need    = off_packed + (size_t)NBKT * PCAP * sizeof(uint2);

    // expected per-bucket load 2m/NBKT must sit well under PCAP (+12 sigma at 1.6M)
    const bool path12 = (d == 8192) && (m > 0) && (m <= 1700000) &&
                        (d_ws != nullptr) && (ws_size >= ws_need);

    if (path12) {
        char* ws = (char*)d_ws;
        int*   gcur   = (int*)ws;
        int*   ghdr   = (int*)(ws + off_ghdr);
        uint2* glist  = (uint2*)(ws + off_glist);
        uint2* packed = (uint2*)(ws + off_packed);

        const int nblk = (m + P1_PAIRS - 1) / P1_PAIRS;   // 391

        hipMemsetAsync(ws, 0, hdr_bytes, stream);
        p1_kernel<<<nblk, 1024, 0, stream>>>(idx, V_int, iscale, m,
                                             packed, gcur, glist, ghdr);
        p2_kernel<<<NBKT, 256, 0, stream>>>(out, h_local, packed, gcur,
                                            glist, ghdr);
    } else if (pow2 && d >= 1024 && d <= 8192 &&
               ((long long)m * 2 / d) < (long long)((d - 2) / 2) / 2) {
        const int cap = (d - 2) / 2;
        init_counts_kernel<<<(d + block - 1) / block, block, 0, stream>>>(out, d, logd);
        bin_kernel<<<(m + block - 1) / block, block, 0, stream>>>(out, idx, V_int,
                                                                  iscale, m, logd, cap);
        rows_kernel<<<d, block, 0, stream>>>(out, h_local, logd, cap);
    } else {
        const long long n = (long long)d * d;
        const long long grid_fill = (n + block - 1) / block;
        fill_diag_kernel<<<(dim3)(unsigned)grid_fill, block, 0, stream>>>(out, h_local, d, n);
        const int grid_sc = (m + block - 1) / block;
        scatter_kernel<<<grid_sc, block, 0, stream>>>(out, idx, V_int, iscale, m, d);
    }
}

// Round 14
// 318.573 us; speedup vs baseline: 1.1216x; 1.0322x over previous
//
#include <hip/hip_runtime.h>
#include <math.h>

// Round 14 (= Round 13 resubmit; infra failed twice, design unvalidated).
// Restore the R6 anchor (measured best, 320.4us) verbatim, with the single
// zero-risk delta: zero_hdr kernel -> 64B hipMemsetAsync.
// Ledger conclusion after 6 structural variants (R7/R8/R10/R11/R12): the
// gather->LDS-scatter->stream-write assembly phase runs at ~3.2 TB/s effective
// on this chip REGARDLESS of block shape/occupancy/packing; deltas between
// variants are fully explained by their read-traffic differences. R6 has the
// minimum traffic (zero read redundancy, bucket==assembler-block) and is the
// optimum of that family.
//  P1 (391 blocks x 1024): bin 4096 pairs -> stage[2048 4-row buckets][8]
//     (64B line slots, sentinel-padded); flush full lines; LDS overflow
//     (~175/blk) -> per-block region, no global atomics on main path.
//  P2 (2048 blocks x 1024): per 4-row band: zero 128KiB LDS -> contiguous 25KB
//     uint4 gather of own slice -> scatter into LDS -> diag -> 128KiB out.
//  P3 (391 blocks): scatter overflow entries into out (~7us, measured-cheap).
// entry = uint2{ key=(row<<13)|col, f32 bits }. d=2^13 -> out flat idx == key.

#define P1_PAIRS 4096
#define NBKT     2048
#define BCAP     8
#define OVB      512
#define SENTK    0xFFFFFFFFu
#define GCAP     65536

// ---------------------------------------------------------------- fused path

__global__ __launch_bounds__(1024) void p1_kernel(
    const int*   __restrict__ idx,     // [2, M] int32
    const float* __restrict__ vals,    // [M]
    float scale, int m, int nblk,
    uint2* __restrict__ region1,       // [NBKT][nblk][BCAP]
    uint2* __restrict__ ovf,           // [nblk][OVB]
    int*   __restrict__ ovfc,          // [nblk]
    uint2* __restrict__ glist,         // [GCAP]  (never-path)
    int*   __restrict__ ghdr)
{
    __shared__ uint2 stage[NBKT][BCAP];    // 128 KiB
    __shared__ int   cnt[NBKT];            // 8 KiB
    __shared__ uint2 ovfst[OVB];           // 4 KiB
    __shared__ int   ovfn;

    uint2* sflat = &stage[0][0];
    for (int f = threadIdx.x; f < NBKT * BCAP; f += 1024)
        sflat[f] = make_uint2(SENTK, 0u);
    for (int b = threadIdx.x; b < NBKT; b += 1024) cnt[b] = 0;
    if (threadIdx.x == 0) ovfn = 0;
    __syncthreads();

    const int blk  = blockIdx.x;
    const int base = blk * P1_PAIRS;
#pragma unroll
    for (int it = 0; it < P1_PAIRS / 1024; ++it) {
        int k = base + it * 1024 + threadIdx.x;
        if (k < m) {
            int i = idx[k];
            int j = idx[m + k];
            unsigned vb = __float_as_uint(vals[k] * scale);

            unsigned k1 = ((unsigned)i << 13) | (unsigned)j;
            int b1 = i >> 2;
            int p = atomicAdd(&cnt[b1], 1);
            if (p < BCAP) stage[b1][p] = make_uint2(k1, vb);
            else {
                int q = atomicAdd(&ovfn, 1);
                if (q < OVB) ovfst[q] = make_uint2(k1, vb);
                else { int g = atomicAdd(ghdr, 1); if (g < GCAP) glist[g] = make_uint2(k1, vb); }
            }

            unsigned k2 = ((unsigned)j << 13) | (unsigned)i;
            int b2 = j >> 2;
            p = atomicAdd(&cnt[b2], 1);
            if (p < BCAP) stage[b2][p] = make_uint2(k2, vb);
            else {
                int q = atomicAdd(&ovfn, 1);
                if (q < OVB) ovfst[q] = make_uint2(k2, vb);
                else { int g = atomicAdd(ghdr, 1); if (g < GCAP) glist[g] = make_uint2(k2, vb); }
            }
        }
    }
    __syncthreads();

    // flush all slots: each bucket's 8 entries = one aligned 64B line
    for (int f = threadIdx.x; f < NBKT * BCAP; f += 1024) {
        int b = f >> 3, e = f & 7;
        region1[((long long)b * nblk + blk) * BCAP + e] = sflat[f];
    }
    // flush per-block LDS overflow (no atomics, per-block region)
    int n = ovfn; if (n > OVB) n = OVB;
    for (int e = threadIdx.x; e < n; e += 1024)
        ovf[(long long)blk * OVB + e] = ovfst[e];
    if (threadIdx.x == 0) ovfc[blk] = n;
}

__global__ __launch_bounds__(1024) void p2_kernel(
    float* __restrict__ out,
    const float* __restrict__ h_local,
    const uint2* __restrict__ region1,
    int nblk)
{
    __shared__ float srow[4 * 8192];               // 128 KiB: one 4-row band
    float4* s4 = reinterpret_cast<float4*>(srow);
    const int band = blockIdx.x;

    for (int c = threadIdx.x; c < 8192; c += 1024)
        s4[c] = make_float4(0.f, 0.f, 0.f, 0.f);
    __syncthreads();

    // contiguous 25KB gather of this band's slice (2 entries / uint4)
    const uint4* src = reinterpret_cast<const uint4*>(
        region1 + (long long)band * nblk * BCAP);
    const int n2 = (nblk * BCAP) >> 1;
    for (int e = threadIdx.x; e < n2; e += 1024) {
        uint4 en = src[e];
        if (en.x != SENTK) srow[en.x & 0x7FFF] = __uint_as_float(en.y);
        if (en.z != SENTK) srow[en.z & 0x7FFF] = __uint_as_float(en.w);
    }
    if (threadIdx.x < 4) {
        int r = (band << 2) + threadIdx.x;
        srow[((unsigned)threadIdx.x << 13) | (unsigned)r] = h_local[r];
    }
    __syncthreads();

    float4* orow = reinterpret_cast<float4*>(out + ((long long)band << 15));
    for (int c = threadIdx.x; c < 8192; c += 1024)
        orow[c] = s4[c];
}

__global__ __launch_bounds__(256) void ovf_scatter_kernel(
    float* __restrict__ out,
    const uint2* __restrict__ ovf,     // [nblk][OVB]
    const int*   __restrict__ ovfc,    // [nblk]
    const uint2* __restrict__ glist,
    const int*   __restrict__ ghdr)
{
    const int blk = blockIdx.x;
    int n = ovfc[blk]; if (n > OVB) n = OVB;
    for (int e = threadIdx.x; e < n; e += 256) {
        uint2 en = ovf[(long long)blk * OVB + e];
        out[en.x] = __uint_as_float(en.y);         // d=2^13: flat index == key
    }
    if (blk == 0) {                                // never-path spill
        int g = ghdr[0]; if (g > GCAP) g = GCAP;
        for (int e = threadIdx.x; e < g; e += 256) {
            uint2 en = glist[e];
            out[en.x] = __uint_as_float(en.y);
        }
    }
}

// ---------------------------------------------------------------- fallbacks

__global__ __launch_bounds__(256) void init_counts_kernel(
    float* __restrict__ out, int d, int logd)
{
    int r = blockIdx.x * blockDim.x + threadIdx.x;
    if (r < d) reinterpret_cast<int*>(out)[(long long)r << logd] = 0;
}

__global__ __launch_bounds__(256) void bin_kernel(
    float* __restrict__ out,
    const int*   __restrict__ idx,
    const float* __restrict__ vals,
    float scale, int m, int logd, int cap)
{
    int k = blockIdx.x * blockDim.x + threadIdx.x;
    if (k >= m) return;
    int i = idx[k];
    int j = idx[m + k];
    unsigned vb = __float_as_uint(vals[k] * scale);
    int* cnt_i = reinterpret_cast<int*>(out) + ((long long)i << logd);
    int* cnt_j = reinterpret_cast<int*>(out) + ((long long)j << logd);
    int p1 = atomicAdd(cnt_i, 1);
    if (p1 < cap)
        *reinterpret_cast<uint2*>(out + ((long long)i << logd) + 2 + 2 * p1) =
            make_uint2((unsigned)j, vb);
    int p2 = atomicAdd(cnt_j, 1);
    if (p2 < cap)
        *reinterpret_cast<uint2*>(out + ((long long)j << logd) + 2 + 2 * p2) =
            make_uint2((unsigned)i, vb);
}

__global__ __launch_bounds__(256) void rows_kernel(
    float* __restrict__ out,
    const float* __restrict__ h_local,
    int logd, int cap)
{
    __shared__ float srow[8192];
    const int d  = 1 << logd;
    const int n4 = d >> 2;
    float4* s4 = reinterpret_cast<float4*>(srow);
    const int r = blockIdx.x;
    float* grow = out + ((long long)r << logd);
    const float4 z = make_float4(0.f, 0.f, 0.f, 0.f);
    for (int c = threadIdx.x; c < n4; c += blockDim.x) s4[c] = z;
    __syncthreads();
    int cnt = reinterpret_cast<const int*>(grow)[0];
    if (cnt > cap) cnt = cap;
    const uint2* eb = reinterpret_cast<const uint2*>(grow + 2);
    for (int e = threadIdx.x; e < cnt; e += blockDim.x) {
        uint2 p = eb[e];
        srow[p.x] = __uint_as_float(p.y);
    }
    if (threadIdx.x == 0) srow[r] = h_local[r];
    __syncthreads();
    for (int c = threadIdx.x; c < n4; c += blockDim.x)
        reinterpret_cast<float4*>(grow)[c] = s4[c];
}

__global__ __launch_bounds__(256) void fill_diag_kernel(
    float* __restrict__ out, const float* __restrict__ h_local,
    int d, long long n)
{
    long long t = (long long)blockIdx.x * blockDim.x + threadIdx.x;
    if (t >= n) return;
    long long row = t / d;
    long long col = t - row * d;
    out[t] = (row == col) ? h_local[row] : 0.f;
}

__global__ __launch_bounds__(256) void scatter_kernel(
    float* __restrict__ out,
    const int* __restrict__ idx,
    const float* __restrict__ vals,
    float scale, int m, int d)
{
    int k = blockIdx.x * blockDim.x + threadIdx.x;
    if (k >= m) return;
    int i = idx[k];
    int j = idx[m + k];
    float v = vals[k] * scale;
    out[(long long)i * d + j] = v;
    out[(long long)j * d + i] = v;
}

// ---------------------------------------------------------------- launch

extern "C" void kernel_launch(void* const* d_in, const int* in_sizes, int n_in,
                              void* d_out, int out_size, void* d_ws, size_t ws_size,
                              hipStream_t stream) {
    const float* h_local = (const float*)d_in[0];
    const float* V_int   = (const float*)d_in[1];
    const int*   idx     = (const int*)d_in[2];

    const int d = in_sizes[0];            // 8192
    const int m = in_sizes[1];            // 1,600,000

    int logd = 0;
    while ((1 << logd) < d) ++logd;
    const bool pow2 = ((1 << logd) == d);

    const float iscale = (float)(1.0 - 0.2 / sqrt(log((double)d)));
    float* out = (float*)d_out;
    const int block = 256;

    const int nblk = (m + P1_PAIRS - 1) / P1_PAIRS;      // 391 for m=1.6M

    // ws layout (bytes, aligned): [ghdr @0][ovfc @4096][glist][ovf][region1]
    const size_t off_ovfc  = 4096;
    const size_t off_glist = off_ovfc + (((size_t)nblk * 4 + 4095) & ~(size_t)4095);
    const size_t off_ovf   = off_glist + (size_t)GCAP * sizeof(uint2);
    const size_t off_r1    = off_ovf + (((size_t)nblk * OVB * sizeof(uint2) + 4095)
                                        & ~(size_t)4095);
    const size_t ws_need   = off_r1 + (size_t)NBKT * nblk * BCAP * sizeof(uint2);

    const bool path14 = (d == 8192) && (m > 0) && (m <= 1900000) &&
                        (d_ws != nullptr) && (ws_size >= ws_need);

    if (path14) {
        char* ws = (char*)d_ws;
        int*   ghdr    = (int*)ws;
        int*   ovfc    = (int*)(ws + off_ovfc);
        uint2* glist   = (uint2*)(ws + off_glist);
        uint2* ovf     = (uint2*)(ws + off_ovf);
        uint2* region1 = (uint2*)(ws + off_r1);

        // ghdr zero (64B; ovfc is written unconditionally by p1)
        hipMemsetAsync(ws, 0, 64, stream);
        p1_kernel<<<nblk, 1024, 0, stream>>>(idx, V_int, iscale, m, nblk,
                                             region1, ovf, ovfc, glist, ghdr);
        p2_kernel<<<NBKT, 1024, 0, stream>>>(out, h_local, region1, nblk);
        ovf_scatter_kernel<<<nblk, 256, 0, stream>>>(out, ovf, ovfc, glist, ghdr);
    } else if (pow2 && d >= 1024 && d <= 8192 &&
               ((long long)m * 2 / d) < (long long)((d - 2) / 2) / 2) {
        const int cap = (d - 2) / 2;
        init_counts_kernel<<<(d + block - 1) / block, block, 0, stream>>>(out, d, logd);
        bin_kernel<<<(m + block - 1) / block, block, 0, stream>>>(out, idx, V_int,
                                                                  iscale, m, logd, cap);
        rows_kernel<<<d, block, 0, stream>>>(out, h_local, logd, cap);
    } else {
        const long long n = (long long)d * d;
        const long long grid_fill = (n + block - 1) / block;
        fill_diag_kernel<<<(dim3)(unsigned)grid_fill, block, 0, stream>>>(out, h_local, d, n);
        const int grid_sc = (m + block - 1) / block;
        scatter_kernel<<<grid_sc, block, 0, stream>>>(out, idx, V_int, iscale, m, d);
    }
}